// Round 14
// baseline (185.344 us; speedup 1.0000x reference)
//
#include <hip/hip_runtime.h>
#include <hip/hip_bf16.h>

// Problem constants (ResNet-50 CBP head)
#define BATCH 8
#define CH    2048
#define LSP   784          // H*W = 28*28
#define KPAD  832          // pad K to 13*64: full-128B-line k-stages
#define KSTAGE 13          // k-stages of BK=64 (2 MFMA k-substeps each)
#define DDIM  8192         // count-sketch dim (power of 2)
#define NCLS  200
#define NTILE 16           // 2048/128 tiles per dim
#define NGRID 256          // gram grid: 1 block/CU (96 KB LDS), one round
#define NUNIT 1024         // job units: 64 double-diag + 960 off-diag
#define NSLOT 32           // part slots per batch (one per block, exclusive)
#define FXINV (1.0f/8192.0f)  // fixed-point scale 2^13 (64*128 in meta)

typedef _Float16 f16x8 __attribute__((ext_vector_type(8)));
typedef float    f32x4 __attribute__((ext_vector_type(4)));

#define FATOMIC(p, v) unsafeAtomicAdd((p), (v))

// ---------------------------------------------------------------------------
// Kernel 1: convert x (fp32 [B,C,784]) to fp16 [B,C,KPAD] (zero-pad K).
// 8 elems/thread (2x float4 load, 1x 16B f16x8 store). Also: zero norm,
// bias-seed logits, build packed scatter-meta metaG[c] =
// (s1[c]*64, h1[c], s2[c]*128, h2[c]) (2^13 fixed-point scale rides the
// s1*s2 product), and -- ONLY in atomic-fallback mode -- zero part.
// ---------------------------------------------------------------------------
__global__ __launch_bounds__(256) void split_kernel(
    const float* __restrict__ x,
    _Float16* __restrict__ xh,
    float* __restrict__ part, float* __restrict__ norm,
    const float* __restrict__ s1, const int* __restrict__ h1,
    const float* __restrict__ s2, const int* __restrict__ h2,
    float4* __restrict__ metaG,
    const float* __restrict__ bc, float* __restrict__ out,
    int exclusive)
{
    int idx = blockIdx.x * 256 + threadIdx.x;          // vec8 index
    if (!exclusive && idx < NSLOT * BATCH * DDIM / 4)  // zero part (fallback)
        *(float4*)&part[idx * 4] = make_float4(0.f, 0.f, 0.f, 0.f);
    if (idx < CH)
        metaG[idx] = make_float4(s1[idx] * 64.0f, __int_as_float(h1[idx]),
                                 s2[idx] * 128.0f, __int_as_float(h2[idx]));
    if (idx < BATCH) norm[idx] = 0.0f;
    if (idx < BATCH * NCLS) out[idx] = bc[idx % NCLS]; // bias-seed logits
    if (idx >= BATCH * CH * KPAD / 8) return;
    int v  = idx * 8;
    int bc_ = v / KPAD;
    int l  = v - bc_ * KPAD;                           // multiple of 8
    f16x8 hv = {0, 0, 0, 0, 0, 0, 0, 0};
    if (l < LSP) {                                     // LSP%8==0: uniform per vec
        const float* xp = &x[(size_t)bc_ * LSP + l];
        float4 a = *(const float4*)xp;
        float4 c = *(const float4*)(xp + 4);
        hv[0] = (_Float16)a.x; hv[1] = (_Float16)a.y;
        hv[2] = (_Float16)a.z; hv[3] = (_Float16)a.w;
        hv[4] = (_Float16)c.x; hv[5] = (_Float16)c.y;
        hv[6] = (_Float16)c.z; hv[7] = (_Float16)c.w;
    }
    *(f16x8*)&xh[v] = hv;
}

// ---------------------------------------------------------------------------
// Kernel 2: symmetric Gram tiles + count-sketch scatter (int32 LDS histogram).
// R14: BK=64 FULL-LINE DOUBLE-BUFFER. R13's 49.9us decomposes as ~18us DS
// reads + ~10us scatter + MFMA vs ~50 measured -> ~55% is the per-stage
// vmcnt(0) drain at __syncthreads (L2->LDS round trip exposed 28x/CU).
// R7/R9 failed for diagnosed confounds (ds_write swap; half-line loads);
// the clean fix: double-buffer the 64-half-wide tiles. LDS = smA[2]+smB[2]
// (64 KB) + bins (32 KB) = 96 KB -> 1 block/CU, grid 256, 4 units/block.
// Per stage: issue s+1 (or next pair's stage 0) into alternate parity ->
// vmcnt(8/4) counted wait (next-stage loads STAY IN FLIGHT across the raw
// s_barrier) -> compute -> s_barrier. R9-validated sync skeleton; R6-proven
// full-line stage64; R13-proven job list / shared bins / single flush.
// batch = bid&7 (one batch per XCD; 256%8==0).
// ---------------------------------------------------------------------------
__device__ __forceinline__ void stage64(
    const _Float16* __restrict__ src,   // xh + (b*CH + tile*128)*KPAD
    unsigned short* lds,                // 128x64-half tile, linear
    int wv, int lane, int s)
{
    const int rowi = lane >> 3;             // 0..7: row within instruction
    const int gc   = (lane & 7) ^ rowi;     // pre-swizzled global 8-half chunk
    const _Float16* g0 = src + (size_t)rowi * KPAD + s * 64 + gc * 8;
#pragma unroll
    for (int q = 0; q < 4; ++q) {
        const int r0 = wv * 32 + q * 8;     // 8 rows per instruction
        __builtin_amdgcn_global_load_lds(
            (__attribute__((address_space(1))) void*)(g0 + (size_t)r0 * KPAD),
            (__attribute__((address_space(3))) void*)(lds + r0 * 64),
            16, 0, 0);
    }
}

__global__ __launch_bounds__(256) void gram_scatter_kernel(
    const _Float16* __restrict__ xh,
    const float4* __restrict__ metaG,
    float* __restrict__ part,
    int exclusive)
{
    __shared__ __align__(16) unsigned short smA[2][128 * 64];  // 32 KB
    __shared__ __align__(16) unsigned short smB[2][128 * 64];  // 32 KB
    __shared__ __align__(16) int bins[DDIM];                   // 32 KB

    const int tid  = threadIdx.x;
    const int lane = tid & 63;
    const int wv   = tid >> 6;
    const int bid  = blockIdx.x;
    const int b    = bid & 7;              // batch in low bits -> one batch/XCD

    for (int i = tid; i < DDIM; i += 256) bins[i] = 0;
    // (13 stage barriers precede the first ds_add -> init is ordered)

    // Flatten this block's 4 units into a pair list (5 pairs if bid<64).
    int npairs = 0, tMl[5], tNl[5];
#pragma unroll 1
    for (int jj = 0; jj < 4; ++jj) {
        const int unit = bid + jj * NGRID;
        if (unit < 64) {                   // double-diag unit (only jj==0)
            const int t2 = (unit >> 3) * 2;
            tMl[npairs] = tNl[npairs] = t2;     ++npairs;
            tMl[npairs] = tNl[npairs] = t2 + 1; ++npairs;
        } else {                           // one strict-upper off-diag pair
            int i = (unit - 64) >> 3;      // 0..119
            int tM = 0, tN = 0;
#pragma unroll 1
            for (int t = 0; t < NTILE - 1; ++t) {
                int c = NTILE - 1 - t;
                if (i < c) { tM = t; tN = t + 1 + i; break; }
                i -= c;
            }
            tMl[npairs] = tM; tNl[npairs] = tN; ++npairs;
        }
    }

    const int wrow = (wv >> 1) * 64;    // wave's 64x64 subtile origin
    const int wcol = (wv & 1) * 64;
    const int rsel = lane & 15;
    const int khi  = lane >> 4;         // k 8-half group within a k-substep

    // Prologue: prefetch pair 0, stage 0 into parity 0.
    {
        const _Float16* a0 = xh + ((size_t)b * CH + (size_t)tMl[0] * 128) * KPAD;
        stage64(a0, smA[0], wv, lane, 0);
        if (tMl[0] != tNl[0]) {
            const _Float16* b0 = xh + ((size_t)b * CH + (size_t)tNl[0] * 128) * KPAD;
            stage64(b0, smB[0], wv, lane, 0);
        }
    }

    int g = 0;                          // global stage parity across pairs

#pragma unroll 1
    for (int p = 0; p < npairs; ++p) {
        const int tM = tMl[p], tN = tNl[p];
        const bool diag = (tM == tN);

        const _Float16* srcA = xh + ((size_t)b * CH + (size_t)tM * 128) * KPAD;
        const _Float16* srcB = xh + ((size_t)b * CH + (size_t)tN * 128) * KPAD;

        f32x4 acc[4][4];
        const f32x4 zv = {0.0f, 0.0f, 0.0f, 0.0f};
#pragma unroll
        for (int mi = 0; mi < 4; ++mi)
#pragma unroll
            for (int ni = 0; ni < 4; ++ni) acc[mi][ni] = zv;

#pragma unroll 1
        for (int s = 0; s < KSTAGE; ++s) {
            const int curb = g & 1, nxtb = curb ^ 1;
            // Issue the NEXT stage's loads into the alternate parity. That
            // buffer was last read at stage g-1, whose end-of-stage barrier
            // every wave has passed -> safe to overwrite.
            int k = 0;
            if (s + 1 < KSTAGE) {
                stage64(srcA, smA[nxtb], wv, lane, s + 1);
                if (!diag) { stage64(srcB, smB[nxtb], wv, lane, s + 1); k = 8; }
                else k = 4;
            } else if (p + 1 < npairs) {       // next pair's stage 0
                const int nM = tMl[p + 1], nN = tNl[p + 1];
                const _Float16* nA = xh + ((size_t)b * CH + (size_t)nM * 128) * KPAD;
                stage64(nA, smA[nxtb], wv, lane, 0);
                if (nM != nN) {
                    const _Float16* nB = xh + ((size_t)b * CH + (size_t)nN * 128) * KPAD;
                    stage64(nB, smB[nxtb], wv, lane, 0);
                    k = 8;
                } else k = 4;
            }
            __builtin_amdgcn_sched_barrier(0);
            // Counted wait: only the k just-issued loads may remain in
            // flight -> current stage's loads have all landed. Never
            // vmcnt(0) in the steady state.
            if (k == 8)      asm volatile("s_waitcnt vmcnt(8)" ::: "memory");
            else if (k == 4) asm volatile("s_waitcnt vmcnt(4)" ::: "memory");
            else             asm volatile("s_waitcnt vmcnt(0)" ::: "memory");
            __builtin_amdgcn_s_barrier();      // all waves' stage-g loads in
            __builtin_amdgcn_sched_barrier(0);

            const unsigned short* bufA = smA[curb];
            const unsigned short* bufB = diag ? smA[curb] : smB[curb];
#pragma unroll
            for (int t = 0; t < 2; ++t) {
                // swizzled chunk: global chunk (t*4+khi) lives at LDS chunk
                // (t*4+khi)^(row&7); row&7 == rsel&7 for all fragments here.
                const int co = ((((t << 2) + khi) ^ (rsel & 7)) << 3);
                f16x8 ah[4], bh[4];
#pragma unroll
                for (int i = 0; i < 4; ++i) {
                    ah[i] = *(const f16x8*)&bufA[(wrow + i * 16 + rsel) * 64 + co];
                    bh[i] = *(const f16x8*)&bufB[(wcol + i * 16 + rsel) * 64 + co];
                }
#pragma unroll
                for (int mi = 0; mi < 4; ++mi)
#pragma unroll
                    for (int ni = 0; ni < 4; ++ni)
                        acc[mi][ni] = __builtin_amdgcn_mfma_f32_16x16x32_f16(
                            ah[mi], bh[ni], acc[mi][ni], 0, 0, 0);
            }
            __builtin_amdgcn_sched_barrier(0);
            __builtin_amdgcn_s_barrier();      // reads done before overwrite
            ++g;
        }

        // Scatter pair p into the shared int histogram. The meta VMEM loads
        // below force-drain the prefetched next-pair loads (in-order vmcnt),
        // which is harmless: they had a full stage of head start and the
        // scatter is ~10x their remaining latency.
        // C/D layout (m89): col = lane&15, row = (lane>>4)*4 + reg.
        const int c2b = tN * 128 + wcol + rsel;
        int   h1c[4], h2c[4]; float s1c[4], s2c[4];
#pragma unroll
        for (int ni = 0; ni < 4; ++ni) {
            float4 cm = metaG[c2b + ni * 16];
            s1c[ni] = cm.x; h1c[ni] = __float_as_int(cm.y);
            s2c[ni] = cm.z; h2c[ni] = __float_as_int(cm.w);
        }
        const int rowbase = tM * 128 + wrow + (khi << 2);
#pragma unroll
        for (int mi = 0; mi < 4; ++mi) {
            float4 rm[4];
#pragma unroll
            for (int r = 0; r < 4; ++r) rm[r] = metaG[rowbase + mi * 16 + r];
#pragma unroll
            for (int r = 0; r < 4; ++r) {
                const float s1r = rm[r].x, s2r = rm[r].z;
                const int h1r = __float_as_int(rm[r].y);
                const int h2r = __float_as_int(rm[r].w);
#pragma unroll
                for (int ni = 0; ni < 4; ++ni) {
                    float g2 = acc[mi][ni][r];
                    atomicAdd(&bins[(h1r + h2c[ni]) & (DDIM - 1)],
                              (int)(s1r * s2c[ni] * g2));
                    if (!diag)
                        atomicAdd(&bins[(h1c[ni] + h2r) & (DDIM - 1)],
                                  (int)(s1c[ni] * s2r * g2));
                }
            }
        }
        // no barrier: the next pair's first stage barrier orders everything
        // (scatter targets bins; staging targets smA/smB -- disjoint).
    }

    __syncthreads();   // all scatters into bins complete

    if (exclusive) {
        // ONE flush per block to its EXCLUSIVE slot (bid>>3, b): plain
        // coalesced float4 stores through L2.
        float* pbase = part + ((size_t)((bid >> 3) * BATCH + b) * DDIM);
#pragma unroll 4
        for (int i = tid; i < DDIM / 4; i += 256) {
            int4 v = *(const int4*)&bins[i * 4];
            float4 f = make_float4((float)v.x * FXINV, (float)v.y * FXINV,
                                   (float)v.z * FXINV, (float)v.w * FXINV);
            *(float4*)&pbase[i * 4] = f;
        }
    } else {
        // Fallback: 32 shared slots, fp32 global atomics, rotated start.
        float* pbase = part + ((size_t)((bid >> 3) * BATCH + b) * DDIM);
        const int rot = (bid & 31) << 8;
        for (int i = tid; i < DDIM; i += 256) {
            int j = (i + rot) & (DDIM - 1);
            int v = bins[j];
            if (v != 0) FATOMIC(&pbase[j], (float)v * FXINV);
        }
    }
}

// ---------------------------------------------------------------------------
// Kernel 3: y[b,d] = sum over 32 part slots (8.4 MB); norm[b] += sum|y|.
// grid 256 x 256: one scalar float per thread, all CUs active.
// batch = blockIdx&7 keeps reads on the XCD whose L2 holds that batch's part.
// NOTE: overwrites y, whose first 32 KB doubled as metaG for the (already
// finished) gram kernel -- intentional workspace reuse.
// ---------------------------------------------------------------------------
__global__ __launch_bounds__(256) void reduce_kernel(
    const float* __restrict__ part, float* __restrict__ y,
    float* __restrict__ norm)
{
    const int tid = threadIdx.x;
    const int b   = blockIdx.x & 7;
    const int d0  = (blockIdx.x >> 3) * 256 + tid;     // scalar float index
    float s = 0.0f;
#pragma unroll 8
    for (int p = 0; p < NSLOT; ++p)
        s += part[((size_t)p * BATCH + b) * DDIM + d0];
    y[(size_t)b * DDIM + d0] = s;
    float ab = fabsf(s);
    __shared__ float red[256];
    red[tid] = ab;
    __syncthreads();
    for (int st = 128; st > 0; st >>= 1) {
        if (tid < st) red[tid] += red[tid + st];
        __syncthreads();
    }
    if (tid == 0) FATOMIC(&norm[b], red[0]);   // sum|y| == sum feat_unnorm^2
}

// ---------------------------------------------------------------------------
// Kernel 4: fused signed-sqrt + L2-normalize + classifier GEMV.
// grid 128: block j owns d in [64j, 64j+64) for all batches (R10: doubles
// the CUs streaming the 6.6 MB W; inv-norm hoisted per batch).
// ---------------------------------------------------------------------------
__global__ __launch_bounds__(256) void logit_kernel(
    const float* __restrict__ y, const float* __restrict__ norm,
    const float* __restrict__ W, float* __restrict__ out)
{
    const int j = blockIdx.x;
    const int tid = threadIdx.x;
    __shared__ float fs[BATCH][64];                    // 2 KB
    __shared__ float inv[BATCH];
    if (tid < BATCH) inv[tid] = 1.0f / fmaxf(sqrtf(norm[tid]), 1e-12f);
    __syncthreads();
    for (int i = tid; i < BATCH * 64; i += 256) {
        int bb = i >> 6, dd = i & 63;
        float v = y[(size_t)bb * DDIM + j * 64 + dd];
        float f = copysignf(sqrtf(fabsf(v)), v) * inv[bb];
        fs[bb][dd] = f;
        out[BATCH * NCLS + (size_t)bb * DDIM + j * 64 + dd] = f;
    }
    __syncthreads();
    if (tid < NCLS) {
        float a[BATCH];
#pragma unroll
        for (int bb = 0; bb < BATCH; ++bb) a[bb] = 0.0f;
        for (int dd = 0; dd < 64; ++dd) {
            float w = W[(size_t)(j * 64 + dd) * NCLS + tid];
#pragma unroll
            for (int bb = 0; bb < BATCH; ++bb) a[bb] += fs[bb][dd] * w;
        }
#pragma unroll
        for (int bb = 0; bb < BATCH; ++bb)
            FATOMIC(&out[bb * NCLS + tid], a[bb]);
    }
}

// ---------------------------------------------------------------------------
extern "C" void kernel_launch(void* const* d_in, const int* in_sizes, int n_in,
                              void* d_out, int out_size, void* d_ws, size_t ws_size,
                              hipStream_t stream)
{
    const float* x  = (const float*)d_in[0];
    const float* s1 = (const float*)d_in[1];
    const float* s2 = (const float*)d_in[2];
    const float* W  = (const float*)d_in[3];
    const float* bc = (const float*)d_in[4];
    const int*   h1 = (const int*)d_in[5];
    const int*   h2 = (const int*)d_in[6];
    float* out = (float*)d_out;

    const size_t ybytes  = (size_t)BATCH * DDIM * sizeof(float);
    const size_t xhbytes = (size_t)BATCH * CH * KPAD * sizeof(_Float16);
    const size_t partbytes = (size_t)NSLOT * BATCH * DDIM * sizeof(float);

    // exclusive: plain-store flush, no part init. fallback: atomic flush.
    const int exclusive = (ws_size >= partbytes + ybytes + 128 + xhbytes);

    // ws layout: part (8.4MB) | y (first 32KB doubles as metaG until
    // reduce) | norm | xh (27.3MB)  ~ 36 MB total
    char* ws = (char*)d_ws;
    float* part = (float*)ws;
    float* y    = (float*)(ws + partbytes);
    float4* metaG = (float4*)(ws + partbytes);         // overlay on y region
    float* norm = (float*)(ws + partbytes + ybytes);
    _Float16* xh = (_Float16*)(ws + partbytes + ybytes + 128);

    split_kernel<<<(BATCH * CH * KPAD / 8 + 255) / 256, 256, 0, stream>>>(
        x, xh, part, norm, s1, h1, s2, h2, metaG, bc, out, exclusive);

    gram_scatter_kernel<<<NGRID, 256, 0, stream>>>(
        xh, metaG, part, exclusive);

    reduce_kernel<<<256, 256, 0, stream>>>(part, y, norm);

    logit_kernel<<<128, 256, 0, stream>>>(y, norm, W, out);
}

// Round 15
// 161.923 us; speedup vs baseline: 1.1446x; 1.1446x over previous
//
#include <hip/hip_runtime.h>
#include <hip/hip_bf16.h>

// Problem constants (ResNet-50 CBP head)
#define BATCH 8
#define CH    2048
#define LSP   784          // H*W = 28*28
#define KPAD  832          // pad K to 13*64: full-128B-line k-stages
#define KSTAGE 13          // k-stages of BK=64 (2 MFMA k-substeps each)
#define DDIM  8192         // count-sketch dim (power of 2)
#define NCLS  200
#define NTILE 16           // 2048/128 tiles per dim
#define NGRID 512          // gram grid: ONE fully-resident round (2/CU)
#define NUNIT 1024         // job units: 64 double-diag + 960 off-diag
#define NSLOT 64           // part slots per batch (one per block, exclusive)
#define FXINV (1.0f/8192.0f)  // fixed-point scale 2^13 (64*128 in meta)

typedef _Float16 f16x8 __attribute__((ext_vector_type(8)));
typedef float    f32x4 __attribute__((ext_vector_type(4)));

#define FATOMIC(p, v) unsafeAtomicAdd((p), (v))

// ---------------------------------------------------------------------------
// R15 = R13 verbatim (best measured: 162.1 us; gram 49.9 us).
// R14 (1 block/CU BK=64 double-buffer) regressed to 73.6 us: the co-resident
// second block's TLP at 2 blocks/CU hides more latency than any explicit
// pipeline that costs occupancy. Five structural attacks on the stage-latency
// gap (R7/R9/R14 pipelines, R8 packing, R12 fusion) all lost to this shape.
// ---------------------------------------------------------------------------

// ---------------------------------------------------------------------------
// Kernel 1: convert x (fp32 [B,C,784]) to fp16 [B,C,KPAD] (zero-pad K).
// 8 elems/thread (2x float4 load, 1x 16B f16x8 store). Also: zero norm,
// bias-seed logits, build packed scatter-meta metaG[c] =
// (s1[c]*64, h1[c], s2[c]*128, h2[c]) (2^13 fixed-point scale rides the
// s1*s2 product), and -- ONLY in atomic-fallback mode -- zero part.
// ---------------------------------------------------------------------------
__global__ __launch_bounds__(256) void split_kernel(
    const float* __restrict__ x,
    _Float16* __restrict__ xh,
    float* __restrict__ part, float* __restrict__ norm,
    const float* __restrict__ s1, const int* __restrict__ h1,
    const float* __restrict__ s2, const int* __restrict__ h2,
    float4* __restrict__ metaG,
    const float* __restrict__ bc, float* __restrict__ out,
    int exclusive)
{
    int idx = blockIdx.x * 256 + threadIdx.x;          // vec8 index
    if (!exclusive && idx < NSLOT * BATCH * DDIM / 4)  // zero part (fallback)
        *(float4*)&part[idx * 4] = make_float4(0.f, 0.f, 0.f, 0.f);
    if (idx < CH)
        metaG[idx] = make_float4(s1[idx] * 64.0f, __int_as_float(h1[idx]),
                                 s2[idx] * 128.0f, __int_as_float(h2[idx]));
    if (idx < BATCH) norm[idx] = 0.0f;
    if (idx < BATCH * NCLS) out[idx] = bc[idx % NCLS]; // bias-seed logits
    if (idx >= BATCH * CH * KPAD / 8) return;
    int v  = idx * 8;
    int bc_ = v / KPAD;
    int l  = v - bc_ * KPAD;                           // multiple of 8
    f16x8 hv = {0, 0, 0, 0, 0, 0, 0, 0};
    if (l < LSP) {                                     // LSP%8==0: uniform per vec
        const float* xp = &x[(size_t)bc_ * LSP + l];
        float4 a = *(const float4*)xp;
        float4 c = *(const float4*)(xp + 4);
        hv[0] = (_Float16)a.x; hv[1] = (_Float16)a.y;
        hv[2] = (_Float16)a.z; hv[3] = (_Float16)a.w;
        hv[4] = (_Float16)c.x; hv[5] = (_Float16)c.y;
        hv[6] = (_Float16)c.z; hv[7] = (_Float16)c.w;
    }
    *(f16x8*)&xh[v] = hv;
}

// ---------------------------------------------------------------------------
// Kernel 2: symmetric Gram tiles + count-sketch scatter (int32 LDS histogram).
// Single-round grid = 512 (2 blocks/CU, all resident): block bid takes
// job-units {bid, bid+512} from the balanced 1024-unit list (unit<64 = two
// diagonal pairs; else one off-diag pair), accumulates everything into ONE
// bins histogram, flushes ONCE to exclusive slot (bid>>3, bid&7).
// K-loop: R6-proven 13 x {full-128B-line global_load_lds stage, sync,
// 2x(8 XOR-swizzled ds_read_b128 + 16 MFMA), sync}.
// Scatter: banked ds_add_u32 (FP LDS atomics are ~4.5cyc serial; int is
// banked). LDS 64 KB (smA 16 + smB 16 + bins 32) -> 2 blocks/CU.
// batch = bid&7 (one batch per XCD; 512%8==0).
// ---------------------------------------------------------------------------
__device__ __forceinline__ void stage64(
    const _Float16* __restrict__ src,   // xh + (b*CH + tile*128)*KPAD
    unsigned short* lds,                // 128x64-half tile, linear
    int wv, int lane, int s)
{
    const int rowi = lane >> 3;             // 0..7: row within instruction
    const int gc   = (lane & 7) ^ rowi;     // pre-swizzled global 8-half chunk
    const _Float16* g0 = src + (size_t)rowi * KPAD + s * 64 + gc * 8;
#pragma unroll
    for (int q = 0; q < 4; ++q) {
        const int r0 = wv * 32 + q * 8;     // 8 rows per instruction
        __builtin_amdgcn_global_load_lds(
            (__attribute__((address_space(1))) void*)(g0 + (size_t)r0 * KPAD),
            (__attribute__((address_space(3))) void*)(lds + r0 * 64),
            16, 0, 0);
    }
}

__global__ __launch_bounds__(256, 2) void gram_scatter_kernel(
    const _Float16* __restrict__ xh,
    const float4* __restrict__ metaG,
    float* __restrict__ part,
    int exclusive)
{
    __shared__ __align__(16) unsigned short smA[128 * 64];   // 16 KB
    __shared__ __align__(16) unsigned short smB[128 * 64];   // 16 KB
    __shared__ __align__(16) int bins[DDIM];                 // 32 KB

    const int tid  = threadIdx.x;
    const int lane = tid & 63;
    const int wv   = tid >> 6;
    const int bid  = blockIdx.x;
    const int b    = bid & 7;              // batch in low bits -> one batch/XCD

    for (int i = tid; i < DDIM; i += 256) bins[i] = 0;
    // (first stage's __syncthreads orders this before any ds_add)

    const int wrow = (wv >> 1) * 64;    // wave's 64x64 subtile origin
    const int wcol = (wv & 1) * 64;
    const int rsel = lane & 15;
    const int khi  = lane >> 4;         // k 8-half group within a k-substep

#pragma unroll 1
    for (int jj = 0; jj < 2; ++jj) {
        const int unit = bid + jj * NGRID;     // units {bid, bid+512}, same b
        int npair, tMs[2], tNs[2];
        if (unit < 64) {                       // double-diag unit
            const int t2 = (unit >> 3) * 2;
            npair = 2;
            tMs[0] = tNs[0] = t2;
            tMs[1] = tNs[1] = t2 + 1;
        } else {                               // one strict-upper off-diag
            npair = 1;
            int i = (unit - 64) >> 3;          // 0..119
            int tM = 0, tN = 0;
#pragma unroll 1
            for (int t = 0; t < NTILE - 1; ++t) {
                int c = NTILE - 1 - t;         // 15-t strict-upper in row t
                if (i < c) { tM = t; tN = t + 1 + i; break; }
                i -= c;
            }
            tMs[0] = tM; tNs[0] = tN;
        }

#pragma unroll 1
        for (int pp = 0; pp < npair; ++pp) {
            const int tM = tMs[pp], tN = tNs[pp];
            const bool diag = (tM == tN);

            const _Float16* srcA = xh + ((size_t)b * CH + (size_t)tM * 128) * KPAD;
            const _Float16* srcB = xh + ((size_t)b * CH + (size_t)tN * 128) * KPAD;
            const unsigned short* fragB = diag ? smA : smB;

            f32x4 acc[4][4];
            const f32x4 zv = {0.0f, 0.0f, 0.0f, 0.0f};
#pragma unroll
            for (int mi = 0; mi < 4; ++mi)
#pragma unroll
                for (int ni = 0; ni < 4; ++ni) acc[mi][ni] = zv;

            // R6-proven k-loop: 13 x {full-line stage, sync,
            // 2x(8 ds_read_b128 + 16 MFMA), sync}
#pragma unroll 1
            for (int s = 0; s < KSTAGE; ++s) {
                stage64(srcA, smA, wv, lane, s);
                if (!diag) stage64(srcB, smB, wv, lane, s);
                __syncthreads();               // loads landed, all waves ready
#pragma unroll
                for (int t = 0; t < 2; ++t) {
                    // swizzled chunk: global chunk (t*4+khi) lives at LDS
                    // chunk (t*4+khi)^(row&7); row&7 == rsel&7 here.
                    const int co = ((((t << 2) + khi) ^ (rsel & 7)) << 3);
                    f16x8 ah[4], bh[4];
#pragma unroll
                    for (int i = 0; i < 4; ++i) {
                        ah[i] = *(const f16x8*)&smA[(wrow + i * 16 + rsel) * 64 + co];
                        bh[i] = *(const f16x8*)&fragB[(wcol + i * 16 + rsel) * 64 + co];
                    }
#pragma unroll
                    for (int mi = 0; mi < 4; ++mi)
#pragma unroll
                        for (int ni = 0; ni < 4; ++ni)
                            acc[mi][ni] = __builtin_amdgcn_mfma_f32_16x16x32_f16(
                                ah[mi], bh[ni], acc[mi][ni], 0, 0, 0);
                }
                __syncthreads();               // reads done before next stage
            }

            // Column meta: one packed float4 per c2 (VMEM, L2-hot). s-values
            // carry the fixed-point scale (s1*64, s2*128).
            const int c2b = tN * 128 + wcol + rsel;
            int   h1c[4], h2c[4]; float s1c[4], s2c[4];
#pragma unroll
            for (int ni = 0; ni < 4; ++ni) {
                float4 cm = metaG[c2b + ni * 16];
                s1c[ni] = cm.x; h1c[ni] = __float_as_int(cm.y);
                s2c[ni] = cm.z; h2c[ni] = __float_as_int(cm.w);
            }

            // Scatter the 128x128 Gram tile into the LDS int histogram.
            // C/D layout (m89): col = lane&15, row = (lane>>4)*4 + reg.
            // Row meta via VMEM -> zero lgkmcnt-ordered ops between ds_adds.
            // All pairs of this block accumulate into the same bins.
            const int rowbase = tM * 128 + wrow + (khi << 2);
#pragma unroll
            for (int mi = 0; mi < 4; ++mi) {
                float4 rm[4];
#pragma unroll
                for (int r = 0; r < 4; ++r) rm[r] = metaG[rowbase + mi * 16 + r];
#pragma unroll
                for (int r = 0; r < 4; ++r) {
                    const float s1r = rm[r].x, s2r = rm[r].z;
                    const int h1r = __float_as_int(rm[r].y);
                    const int h2r = __float_as_int(rm[r].w);
#pragma unroll
                    for (int ni = 0; ni < 4; ++ni) {
                        float g = acc[mi][ni][r];
                        atomicAdd(&bins[(h1r + h2c[ni]) & (DDIM - 1)],
                                  (int)(s1r * s2c[ni] * g));
                        if (!diag)
                            atomicAdd(&bins[(h1c[ni] + h2r) & (DDIM - 1)],
                                      (int)(s1c[ni] * s2r * g));
                    }
                }
            }
            // no barrier: next pair's stage-0 __syncthreads orders all waves'
            // scatters before smA/smB reuse (disjoint LDS regions anyway).
        }
    }

    __syncthreads();   // all scatters into bins complete

    if (exclusive) {
        // ONE flush per block to its EXCLUSIVE slot (bid>>3, b): plain
        // coalesced float4 stores through L2.
        float* pbase = part + ((size_t)((bid >> 3) * BATCH + b) * DDIM);
#pragma unroll 4
        for (int i = tid; i < DDIM / 4; i += 256) {
            int4 v = *(const int4*)&bins[i * 4];
            float4 f = make_float4((float)v.x * FXINV, (float)v.y * FXINV,
                                   (float)v.z * FXINV, (float)v.w * FXINV);
            *(float4*)&pbase[i * 4] = f;
        }
    } else {
        // Fallback: 64 shared slots, fp32 global atomics, rotated start.
        float* pbase = part + ((size_t)((bid >> 3) * BATCH + b) * DDIM);
        const int rot = (bid & 31) << 8;
        for (int i = tid; i < DDIM; i += 256) {
            int j = (i + rot) & (DDIM - 1);
            int v = bins[j];
            if (v != 0) FATOMIC(&pbase[j], (float)v * FXINV);
        }
    }
}

// ---------------------------------------------------------------------------
// Kernel 3: y[b,d] = sum over 64 part slots (16.8 MB); norm[b] += sum|y|.
// grid 256 x 256: one scalar float per thread, all CUs active.
// batch = blockIdx&7 keeps reads on the XCD whose L2 holds that batch's part.
// NOTE: overwrites y, whose first 32 KB doubled as metaG for the (already
// finished) gram kernel -- intentional workspace reuse.
// ---------------------------------------------------------------------------
__global__ __launch_bounds__(256) void reduce_kernel(
    const float* __restrict__ part, float* __restrict__ y,
    float* __restrict__ norm)
{
    const int tid = threadIdx.x;
    const int b   = blockIdx.x & 7;
    const int d0  = (blockIdx.x >> 3) * 256 + tid;     // scalar float index
    float s = 0.0f;
#pragma unroll 8
    for (int p = 0; p < NSLOT; ++p)
        s += part[((size_t)p * BATCH + b) * DDIM + d0];
    y[(size_t)b * DDIM + d0] = s;
    float ab = fabsf(s);
    __shared__ float red[256];
    red[tid] = ab;
    __syncthreads();
    for (int st = 128; st > 0; st >>= 1) {
        if (tid < st) red[tid] += red[tid + st];
        __syncthreads();
    }
    if (tid == 0) FATOMIC(&norm[b], red[0]);   // sum|y| == sum feat_unnorm^2
}

// ---------------------------------------------------------------------------
// Kernel 4: fused signed-sqrt + L2-normalize + classifier GEMV.
// grid 128: block j owns d in [64j, 64j+64) for all batches (doubles the
// CUs streaming the 6.6 MB W; inv-norm hoisted per batch).
// ---------------------------------------------------------------------------
__global__ __launch_bounds__(256) void logit_kernel(
    const float* __restrict__ y, const float* __restrict__ norm,
    const float* __restrict__ W, float* __restrict__ out)
{
    const int j = blockIdx.x;
    const int tid = threadIdx.x;
    __shared__ float fs[BATCH][64];                    // 2 KB
    __shared__ float inv[BATCH];
    if (tid < BATCH) inv[tid] = 1.0f / fmaxf(sqrtf(norm[tid]), 1e-12f);
    __syncthreads();
    for (int i = tid; i < BATCH * 64; i += 256) {
        int bb = i >> 6, dd = i & 63;
        float v = y[(size_t)bb * DDIM + j * 64 + dd];
        float f = copysignf(sqrtf(fabsf(v)), v) * inv[bb];
        fs[bb][dd] = f;
        out[BATCH * NCLS + (size_t)bb * DDIM + j * 64 + dd] = f;
    }
    __syncthreads();
    if (tid < NCLS) {
        float a[BATCH];
#pragma unroll
        for (int bb = 0; bb < BATCH; ++bb) a[bb] = 0.0f;
        for (int dd = 0; dd < 64; ++dd) {
            float w = W[(size_t)(j * 64 + dd) * NCLS + tid];
#pragma unroll
            for (int bb = 0; bb < BATCH; ++bb) a[bb] += fs[bb][dd] * w;
        }
#pragma unroll
        for (int bb = 0; bb < BATCH; ++bb)
            FATOMIC(&out[bb * NCLS + tid], a[bb]);
    }
}

// ---------------------------------------------------------------------------
extern "C" void kernel_launch(void* const* d_in, const int* in_sizes, int n_in,
                              void* d_out, int out_size, void* d_ws, size_t ws_size,
                              hipStream_t stream)
{
    const float* x  = (const float*)d_in[0];
    const float* s1 = (const float*)d_in[1];
    const float* s2 = (const float*)d_in[2];
    const float* W  = (const float*)d_in[3];
    const float* bc = (const float*)d_in[4];
    const int*   h1 = (const int*)d_in[5];
    const int*   h2 = (const int*)d_in[6];
    float* out = (float*)d_out;

    const size_t ybytes  = (size_t)BATCH * DDIM * sizeof(float);
    const size_t xhbytes = (size_t)BATCH * CH * KPAD * sizeof(_Float16);
    const size_t partbytes = (size_t)NSLOT * BATCH * DDIM * sizeof(float);

    // exclusive: plain-store flush, no part init. fallback: atomic flush.
    const int exclusive = (ws_size >= partbytes + ybytes + 128 + xhbytes);

    // ws layout: part (16.8MB) | y (first 32KB doubles as metaG until
    // reduce) | norm | xh (27.3MB)  ~ 44.4 MB total
    char* ws = (char*)d_ws;
    float* part = (float*)ws;
    float* y    = (float*)(ws + partbytes);
    float4* metaG = (float4*)(ws + partbytes);         // overlay on y region
    float* norm = (float*)(ws + partbytes + ybytes);
    _Float16* xh = (_Float16*)(ws + partbytes + ybytes + 128);

    split_kernel<<<(BATCH * CH * KPAD / 8 + 255) / 256, 256, 0, stream>>>(
        x, xh, part, norm, s1, h1, s2, h2, metaG, bc, out, exclusive);

    gram_scatter_kernel<<<NGRID, 256, 0, stream>>>(
        xh, metaG, part, exclusive);

    reduce_kernel<<<256, 256, 0, stream>>>(part, y, norm);

    logit_kernel<<<128, 256, 0, stream>>>(y, norm, W, out);
}